// Round 15
// baseline (124.144 us; speedup 1.0000x reference)
//
#include <hip/hip_runtime.h>
#include <hip/hip_fp16.h>

// SilkNNUE R14 — R13 with the REAL R12 bug fixed: xs was declared [4][16]
//   (256 B/wave) but written as xs[wave][lane], lane<64 (needs 1024 B/wave).
//   Lanes 16..63 of each wave overwrote other waves' indices and spilled
//   into hT -> deterministic absmax 3.86e-2 in both R12 and R13 (the fence
//   changed nothing -> not a scheduling race). Fix: xs[4][64] (4096 B).
//   Fences kept (zero-cost, make the a2<->hT alias robust).
// Carried: ushort index staging, masked feature-28 round (464 req/row),
// a2 aliases hT, LDS 21504 B -> 7 blocks/CU, merged prepass.

typedef _Float16 h2v_t  __attribute__((ext_vector_type(2)));
typedef _Float16 half8  __attribute__((ext_vector_type(8)));
typedef float    f32x4  __attribute__((ext_vector_type(4)));

constexpr int RPB = 64;   // rows per block

// ---- merged prepass: emb -> fp16 (+ zero pad row), W2/W3 -> fp16 ----------
__global__ __launch_bounds__(256) void prep_fp16(
    const float* __restrict__ emb, const float* __restrict__ W2,
    const float* __restrict__ W3,
    __half2* __restrict__ emb16, _Float16* __restrict__ W2h,
    _Float16* __restrict__ W3h, int npairs_real, int npairs_tot)
{
    int i = blockIdx.x * blockDim.x + threadIdx.x;
    if (i < npairs_tot) {
        float2 v = make_float2(0.f, 0.f);
        if (i < npairs_real) v = ((const float2*)emb)[i];
        emb16[i] = __floats2half2_rn(v.x, v.y);
    }
    if (i < 4096) W2h[i] = (_Float16)W2[i];
    if (i < 2048) W3h[i] = (_Float16)W3[i];
}

// ---------------- fused kernel -------------------------------------------
__global__ __launch_bounds__(256, 7) void nnue_one(
    const int*      __restrict__ x,      // (N,32)
    const __half*   __restrict__ emb16,  // (7425,128) fp16
    const _Float16* __restrict__ W2h,    // (32,128) fp16
    const _Float16* __restrict__ W3h,    // (32,64) fp16
    const float*    __restrict__ b2,
    const float*    __restrict__ b3,
    const float*    __restrict__ W4,     // (64,)
    float*          __restrict__ out, int n)
{
    // per-wave h tile: 16 rows x 17 uint4 (256B data + 16B pad per row).
    // The a2 transpose tile aliases this after the af reads complete.
    __shared__ uint4 hT[4][16 * 17];     // 17408 B
    __shared__ uint4 xs[4][64];          //  4096 B: packed ushort idx [wave][lane]

    const int tid  = threadIdx.x;
    const int lane = tid & 63;
    const int wave = tid >> 6;
    const int row0 = blockIdx.x * RPB;
    const int wrow0 = __builtin_amdgcn_readfirstlane(row0 + wave * 16);

    const int g   = lane >> 4;          // feature subgroup 0..3
    const int sub = lane & 15;          // 16B packet id (= 4*kk + q)
    const unsigned subOff = (unsigned)sub * 16u;

    // ---- stage indices as ushort: lane holds elements 8*lane..8*lane+7 ----
    {
        const int4* xb = (const int4*)(x + (size_t)wrow0 * 32);
        int4 a = xb[lane * 2];
        int4 b = xb[lane * 2 + 1];
        uint4 p;
        p.x = (unsigned)(a.x & 0xffff) | ((unsigned)a.y << 16);
        p.y = (unsigned)(a.z & 0xffff) | ((unsigned)a.w << 16);
        p.z = (unsigned)(b.x & 0xffff) | ((unsigned)b.y << 16);
        p.w = (unsigned)(b.z & 0xffff) | ((unsigned)b.w << 16);
        xs[wave][lane] = p;
    }
    // same-wave DS ordering; no barriers anywhere in this kernel.

    // ---- gather: 7 full rounds + masked feature-28 round ------------------
    #pragma unroll 4
    for (int r = 0; r < 16; ++r) {
        const unsigned short* xrow = (const unsigned short*)&xs[wave][0] + r * 32;

        uint4 v[7];
        #pragma unroll
        for (int b = 0; b < 7; ++b) {
            const int idx = xrow[4 * b + g];         // ds_read_u16 broadcast
            const unsigned off = ((unsigned)idx << 8) + subOff;
            v[b] = *(const uint4*)((const char*)emb16 + off);
        }
        uint4 v7 = make_uint4(0u, 0u, 0u, 0u);
        if (g == 0) {                                // 16 requests, not 64
            const int idx28 = xrow[28];
            v7 = *(const uint4*)((const char*)emb16 +
                                 (((unsigned)idx28) << 8) + subOff);
        }

        h2v_t hacc[4];
        #pragma unroll
        for (int q = 0; q < 4; ++q)
            hacc[q] = __builtin_bit_cast(h2v_t, (&v7.x)[q]);
        #pragma unroll
        for (int b = 0; b < 7; ++b) {
            hacc[0] += __builtin_bit_cast(h2v_t, v[b].x);
            hacc[1] += __builtin_bit_cast(h2v_t, v[b].y);
            hacc[2] += __builtin_bit_cast(h2v_t, v[b].z);
            hacc[3] += __builtin_bit_cast(h2v_t, v[b].w);
        }
        #pragma unroll
        for (int q = 0; q < 4; ++q) {
            unsigned u = __builtin_bit_cast(unsigned, hacc[q]);
            h2v_t t = __builtin_bit_cast(h2v_t, u);
            t += __builtin_bit_cast(h2v_t, (unsigned)__shfl_xor((int)u, 16));
            unsigned u2 = __builtin_bit_cast(unsigned, t);
            t += __builtin_bit_cast(h2v_t, (unsigned)__shfl_xor((int)u2, 32));
            hacc[q] = __builtin_elementwise_max(t, (h2v_t)0);
        }
        if (g == 0) {   // lanes 0..15: packet sub of row r -> hT (2-way, free)
            uint4 o;
            o.x = __builtin_bit_cast(unsigned, hacc[0]);
            o.y = __builtin_bit_cast(unsigned, hacc[1]);
            o.z = __builtin_bit_cast(unsigned, hacc[2]);
            o.w = __builtin_bit_cast(unsigned, hacc[3]);
            hT[wave][r * 17 + sub] = o;
        }
    }

    // ================= dense (per-wave MFMA, same wave's 16 rows) ==========
    const int q  = lane >> 4;     // k-quad
    const int nn = lane & 15;     // A row m / B col n / C col n

    // B-fragments for W2 (L2-hot, identical across waves)
    half8 bw2[2][4];
    #pragma unroll
    for (int nt = 0; nt < 2; ++nt)
        #pragma unroll
        for (int kk = 0; kk < 4; ++kk)
            bw2[nt][kk] = __builtin_bit_cast(half8,
                *(const uint4*)((const char*)W2h +
                    ((nt * 16 + nn) * 128 + kk * 32 + q * 8) * 2));

    // A-fragments from hT: row m = nn, packet 4*kk + q
    half8 af[4];
    #pragma unroll
    for (int kk = 0; kk < 4; ++kk)
        af[kk] = __builtin_bit_cast(half8, hT[wave][nn * 17 + (4 * kk + q)]);

    // layer 2: h2(16x32) = h(16x128) @ W2^T
    f32x4 acc0 = {0.f, 0.f, 0.f, 0.f}, acc1 = {0.f, 0.f, 0.f, 0.f};
    #pragma unroll
    for (int kk = 0; kk < 4; ++kk) {
        acc0 = __builtin_amdgcn_mfma_f32_16x16x32_f16(af[kk], bw2[0][kk], acc0, 0, 0, 0);
        acc1 = __builtin_amdgcn_mfma_f32_16x16x32_f16(af[kk], bw2[1][kk], acc1, 0, 0, 0);
    }
    const float bb0 = b2[nn], bb1 = b2[16 + nn];

    // ---- compiler fence: af (uint4 loads) vs a2 (_Float16 stores) alias ---
    asm volatile("" ::: "memory");

    // CReLU + transpose C-layout -> A-layout via LDS (stride 68 halfs).
    // a2 aliases hT[wave]; fence above pins the af reads before these writes.
    _Float16* a2 = (_Float16*)&hT[wave][0];
    #pragma unroll
    for (int r = 0; r < 4; ++r) {
        const float v0 = acc0[r] + bb0;
        const float v1 = acc1[r] + bb1;
        const int m = q * 4 + r;
        a2[m * 68 + nn]      = (_Float16)fmaxf(v0, 0.f);
        a2[m * 68 + 16 + nn] = (_Float16)fmaxf(v1, 0.f);
        a2[m * 68 + 32 + nn] = (_Float16)fmaxf(-v0, 0.f);
        a2[m * 68 + 48 + nn] = (_Float16)fmaxf(-v1, 0.f);
    }
    asm volatile("" ::: "memory");   // a2 writes before a2f reads

    // B-fragments for W3
    half8 bw3[2][2];
    #pragma unroll
    for (int nt = 0; nt < 2; ++nt)
        #pragma unroll
        for (int kk = 0; kk < 2; ++kk)
            bw3[nt][kk] = __builtin_bit_cast(half8,
                *(const uint4*)((const char*)W3h +
                    ((nt * 16 + nn) * 64 + kk * 32 + q * 8) * 2));

    // A-fragments for layer 3
    half8 a2f[2];
    #pragma unroll
    for (int kk = 0; kk < 2; ++kk) {
        const _Float16* p = &a2[nn * 68 + kk * 32 + q * 8];
        half8 t;
        #pragma unroll
        for (int j = 0; j < 8; ++j) t[j] = p[j];
        a2f[kk] = t;
    }

    // layer 3: h4(16x32) = crelu(h2)(16x64) @ W3^T
    f32x4 acc30 = {0.f, 0.f, 0.f, 0.f}, acc31 = {0.f, 0.f, 0.f, 0.f};
    #pragma unroll
    for (int kk = 0; kk < 2; ++kk) {
        acc30 = __builtin_amdgcn_mfma_f32_16x16x32_f16(a2f[kk], bw3[0][kk], acc30, 0, 0, 0);
        acc31 = __builtin_amdgcn_mfma_f32_16x16x32_f16(a2f[kk], bw3[1][kk], acc31, 0, 0, 0);
    }
    const float bb30 = b3[nn], bb31 = b3[16 + nn];

    // layer 4: out[m] = crelu(h4[m]) . W4
    const float w4a = W4[nn],      w4b = W4[16 + nn];
    const float w4c = W4[32 + nn], w4d = W4[48 + nn];
    float o[4];
    #pragma unroll
    for (int r = 0; r < 4; ++r) {
        const float v0 = acc30[r] + bb30;
        const float v1 = acc31[r] + bb31;
        o[r] = fmaxf(v0, 0.f) * w4a + fmaxf(-v0, 0.f) * w4c
             + fmaxf(v1, 0.f) * w4b + fmaxf(-v1, 0.f) * w4d;
    }
    #pragma unroll
    for (int s = 1; s < 16; s <<= 1) {
        #pragma unroll
        for (int r = 0; r < 4; ++r) o[r] += __shfl_xor(o[r], s);
    }
    if (nn == 0) {
        #pragma unroll
        for (int r = 0; r < 4; ++r) {
            const int row = wrow0 + q * 4 + r;
            if (row < n) out[row] = o[r];
        }
    }
}

// ---------------- fallback (R7 fused, fp32 weights) ------------------------
__global__ __launch_bounds__(256) void nnue_fused(
    const int*    __restrict__ x,
    const __half* __restrict__ emb16,
    const float*  __restrict__ W2, const float* __restrict__ b2,
    const float*  __restrict__ W3, const float* __restrict__ b3,
    const float*  __restrict__ W4,
    float*        __restrict__ out, int n)
{
    __shared__ int     xlds[4][512];
    __shared__ __half2 hbuf[64][65];
    __shared__ float   h2T[32 * 64];
    __shared__ float   obuf[4][64];

    const int tid  = threadIdx.x;
    const int lane = tid & 63;
    const int wave = tid >> 6;
    const int row0 = blockIdx.x * RPB;
    const int wrow0 = __builtin_amdgcn_readfirstlane(row0 + wave * 16);
    const int g   = lane >> 4;
    const int sub = lane & 15;
    const unsigned subOff = (unsigned)sub * 16u;

    {
        const int4* xb = (const int4*)(x + (size_t)wrow0 * 32);
        int4 a = xb[lane * 2];
        int4 b = xb[lane * 2 + 1];
        if ((lane & 3) == 3) { b.y = 7424; b.z = 7424; b.w = 7424; }
        ((int4*)&xlds[wave][0])[lane * 2]     = a;
        ((int4*)&xlds[wave][0])[lane * 2 + 1] = b;
    }

    #pragma unroll 4
    for (int r = 0; r < 16; ++r) {
        const int* xrow = &xlds[wave][r * 32 + g];
        uint4 v[8];
        #pragma unroll
        for (int b = 0; b < 8; ++b) {
            const int idx = xrow[4 * b];
            const unsigned off = ((unsigned)idx << 8) + subOff;
            v[b] = *(const uint4*)((const char*)emb16 + off);
        }
        h2v_t hacc[4];
        #pragma unroll
        for (int q = 0; q < 4; ++q) hacc[q] = (h2v_t)0;
        #pragma unroll
        for (int b = 0; b < 8; ++b) {
            hacc[0] += __builtin_bit_cast(h2v_t, v[b].x);
            hacc[1] += __builtin_bit_cast(h2v_t, v[b].y);
            hacc[2] += __builtin_bit_cast(h2v_t, v[b].z);
            hacc[3] += __builtin_bit_cast(h2v_t, v[b].w);
        }
        #pragma unroll
        for (int q = 0; q < 4; ++q) {
            unsigned u = __builtin_bit_cast(unsigned, hacc[q]);
            h2v_t t = __builtin_bit_cast(h2v_t, u);
            t += __builtin_bit_cast(h2v_t, (unsigned)__shfl_xor((int)u, 16));
            unsigned u2 = __builtin_bit_cast(unsigned, t);
            t += __builtin_bit_cast(h2v_t, (unsigned)__shfl_xor((int)u2, 32));
            hacc[q] = __builtin_elementwise_max(t, (h2v_t)0);
        }
        if (g == 0) {
            const int row = wave * 16 + r;
            #pragma unroll
            for (int q = 0; q < 4; ++q)
                hbuf[row][sub * 4 + q] = __builtin_bit_cast(__half2, hacc[q]);
        }
    }
    __syncthreads();

    {
        const int j0 = wave * 8;
        const int rr = lane;
        float acc[8];
        #pragma unroll
        for (int j = 0; j < 8; ++j) acc[j] = b2[j0 + j];
        #pragma unroll
        for (int d2 = 0; d2 < 64; ++d2) {
            const __half2 hv = hbuf[rr][d2];
            const float vx = __low2float(hv), vy = __high2float(hv);
            #pragma unroll
            for (int j = 0; j < 8; ++j) {
                const float* w = W2 + (size_t)(j0 + j) * 128 + d2 * 2;
                acc[j] = fmaf(vx, w[0], acc[j]);
                acc[j] = fmaf(vy, w[1], acc[j]);
            }
        }
        #pragma unroll
        for (int j = 0; j < 8; ++j) h2T[(j0 + j) * 64 + rr] = acc[j];
    }
    __syncthreads();

    {
        const int j0 = wave * 8;
        const int rr = lane;
        float h2v[32];
        #pragma unroll
        for (int k = 0; k < 32; ++k) h2v[k] = h2T[k * 64 + rr];
        float acc[8];
        #pragma unroll
        for (int j = 0; j < 8; ++j) acc[j] = b3[j0 + j];
        #pragma unroll
        for (int k = 0; k < 32; ++k) {
            const float p = fmaxf(h2v[k], 0.f);
            const float m = fmaxf(-h2v[k], 0.f);
            #pragma unroll
            for (int j = 0; j < 8; ++j) {
                const float* w = W3 + (size_t)(j0 + j) * 64;
                acc[j] = fmaf(p, w[k],      acc[j]);
                acc[j] = fmaf(m, w[32 + k], acc[j]);
            }
        }
        float o = 0.f;
        #pragma unroll
        for (int j = 0; j < 8; ++j) {
            const int jj = j0 + j;
            o = fmaf(fmaxf(acc[j], 0.f),  W4[jj],      o);
            o = fmaf(fmaxf(-acc[j], 0.f), W4[32 + jj], o);
        }
        obuf[wave][rr] = o;
    }
    __syncthreads();

    if (tid < 64) {
        const int row = row0 + tid;
        if (row < n)
            out[row] = obuf[0][tid] + obuf[1][tid] + obuf[2][tid] + obuf[3][tid];
    }
}

extern "C" void kernel_launch(void* const* d_in, const int* in_sizes, int n_in,
                              void* d_out, int out_size, void* d_ws, size_t ws_size,
                              hipStream_t stream) {
    const int*   x   = (const int*)  d_in[0];
    const float* emb = (const float*)d_in[1];
    const float* W2  = (const float*)d_in[2];
    const float* b2  = (const float*)d_in[3];
    const float* W3  = (const float*)d_in[4];
    const float* b3  = (const float*)d_in[5];
    const float* W4  = (const float*)d_in[6];
    float* out = (float*)d_out;
    const int n = out_size;                 // 131072 rows

    const size_t emb_bytes = (size_t)7425 * 256;            // 1,900,800
    const size_t w2h_off   = emb_bytes;                     // 8192 B
    const size_t w3h_off   = w2h_off + 8192;                // 4096 B
    const size_t need      = w3h_off + 4096;
    const bool   fused_ok  = ws_size >= need;

    __half2*  emb16 = (__half2*)d_ws;
    _Float16* W2h   = (_Float16*)((char*)d_ws + w2h_off);
    _Float16* W3h   = (_Float16*)((char*)d_ws + w3h_off);
    const int npairs_real = 7424 * 64;
    const int npairs_tot  = 7425 * 64;

    hipLaunchKernelGGL(prep_fp16, dim3((npairs_tot + 255) / 256), dim3(256),
                       0, stream, emb, W2, W3, emb16, W2h, W3h,
                       npairs_real, npairs_tot);

    if (fused_ok) {
        hipLaunchKernelGGL(nnue_one, dim3((n + RPB - 1) / RPB), dim3(256),
                           0, stream, x, (const __half*)emb16, W2h, W3h,
                           b2, b3, W4, out, n);
    } else {
        hipLaunchKernelGGL(nnue_fused, dim3((n + RPB - 1) / RPB), dim3(256),
                           0, stream, x, (const __half*)emb16, W2, b2, W3, b3,
                           W4, out, n);
    }
}